// Round 1
// baseline (6359.493 us; speedup 1.0000x reference)
//
#include <hip/hip_runtime.h>

#define S_LEN 1024
#define DMODEL 512
#define NHEADS 8
#define DHEAD 64
#define HDIM 2048
#define WIN 64

// ---------------- embed + positional encoding ----------------
// one block per row (b*S+s), 256 threads = 256 (sin,cos) pairs
__global__ void embed_pe_kernel(const int* __restrict__ inputs, const float* __restrict__ emb,
                                float* __restrict__ X) {
  int row = blockIdx.x;          // b*S + s
  int s = row & (S_LEN - 1);
  int t = threadIdx.x;           // pair index 0..255
  int tok = inputs[row];
  float dv = __expf(-logf(10000.0f) * (2.0f * (float)t) / (float)DMODEL);
  float ang = (float)s * dv;
  float sv = sinf(ang);
  float cv = cosf(ang);
  size_t base = (size_t)row * DMODEL + 2 * t;
  X[base]     = emb[(size_t)tok * DMODEL + 2 * t]     + sv;
  X[base + 1] = emb[(size_t)tok * DMODEL + 2 * t + 1] + cv;
}

// ---------------- tiled f32 GEMM: C = A @ W^T + bias (+res, +relu) ----------------
// A[M,K], W[N,K] row-major. 64x64 tile, BK=32, 256 threads, 4x4 per thread.
#define BM 64
#define BN 64
#define BK 32

template <int ACT>
__launch_bounds__(256)
__global__ void gemm_kernel(const float* __restrict__ A, const float* __restrict__ W,
                            const float* __restrict__ bias, const float* __restrict__ res,
                            float* __restrict__ C, int M, int N, int K) {
  __shared__ float As[BK][BM];   // k-major
  __shared__ float Ws[BK][BN];
  const int bm = blockIdx.x * BM;
  const int bn = blockIdx.y * BN;
  const int t = threadIdx.x;
  const int tr = t >> 4;         // 0..15
  const int tc = t & 15;         // 0..15
  float acc[4][4] = {};
  for (int k0 = 0; k0 < K; k0 += BK) {
#pragma unroll
    for (int ld = 0; ld < 2; ++ld) {
      int idx = t + ld * 256;          // 0..511
      int r = idx >> 3;                // 0..63
      int c4 = (idx & 7) << 2;         // 0..28
      float4 av = *(const float4*)(A + (size_t)(bm + r) * K + k0 + c4);
      As[c4 + 0][r] = av.x; As[c4 + 1][r] = av.y; As[c4 + 2][r] = av.z; As[c4 + 3][r] = av.w;
      float4 wv = *(const float4*)(W + (size_t)(bn + r) * K + k0 + c4);
      Ws[c4 + 0][r] = wv.x; Ws[c4 + 1][r] = wv.y; Ws[c4 + 2][r] = wv.z; Ws[c4 + 3][r] = wv.w;
    }
    __syncthreads();
#pragma unroll
    for (int kk = 0; kk < BK; ++kk) {
      float4 a4 = *(const float4*)&As[kk][tr << 2];
      float4 w4 = *(const float4*)&Ws[kk][tc << 2];
      float av[4] = {a4.x, a4.y, a4.z, a4.w};
      float wv[4] = {w4.x, w4.y, w4.z, w4.w};
#pragma unroll
      for (int i = 0; i < 4; ++i)
#pragma unroll
        for (int j = 0; j < 4; ++j) acc[i][j] += av[i] * wv[j];
    }
    __syncthreads();
  }
#pragma unroll
  for (int i = 0; i < 4; ++i) {
    int row = bm + (tr << 2) + i;
    int col = bn + (tc << 2);
    float4 o;
    o.x = acc[i][0] + bias[col + 0];
    o.y = acc[i][1] + bias[col + 1];
    o.z = acc[i][2] + bias[col + 2];
    o.w = acc[i][3] + bias[col + 3];
    if (ACT) {
      o.x = fmaxf(o.x, 0.f); o.y = fmaxf(o.y, 0.f);
      o.z = fmaxf(o.z, 0.f); o.w = fmaxf(o.w, 0.f);
    }
    if (res) {
      float4 rv = *(const float4*)(res + (size_t)row * N + col);
      o.x += rv.x; o.y += rv.y; o.z += rv.z; o.w += rv.w;
    }
    *(float4*)(C + (size_t)row * N + col) = o;
  }
}

// ---------------- per-(b,h) V column sum ----------------
__global__ void vsum_kernel(const float* __restrict__ V, float* __restrict__ VS) {
  int bh = blockIdx.x;           // b*8 + h
  int b = bh >> 3, h = bh & 7;
  int d = threadIdx.x;           // 0..63
  float acc = 0.f;
  const float* vb = V + (size_t)b * S_LEN * DMODEL + h * DHEAD + d;
  for (int s = 0; s < S_LEN; ++s) acc += vb[(size_t)s * DMODEL];
  VS[bh * DHEAD + d] = acc;
}

// ---------------- windowed attention with full-softmax zero correction ----------------
// grid (S/32, H, B), 256 threads = 4 waves, 8 queries per wave
__launch_bounds__(256)
__global__ void attn_kernel(const float* __restrict__ Q, const float* __restrict__ Kp,
                            const float* __restrict__ V, const float* __restrict__ VS,
                            float* __restrict__ O) {
  __shared__ float Ks[160][65];   // padded: bank-conflict-free lane-per-key reads
  __shared__ float Qs[32][64];
  __shared__ float probs[4][128];
  const int qt = blockIdx.x, h = blockIdx.y, b = blockIdx.z;
  const int i0 = qt * 32;
  const int jlo = max(0, i0 - WIN);
  const int jhi = min(S_LEN, i0 + 31 + WIN + 1);
  const int nst = jhi - jlo;      // <= 159
  const int t = threadIdx.x;
  for (int idx = t; idx < nst * 16; idx += 256) {
    int r = idx >> 4, c4 = (idx & 15) << 2;
    float4 kv = *(const float4*)(Kp + (size_t)(b * S_LEN + jlo + r) * DMODEL + h * DHEAD + c4);
    Ks[r][c4 + 0] = kv.x; Ks[r][c4 + 1] = kv.y; Ks[r][c4 + 2] = kv.z; Ks[r][c4 + 3] = kv.w;
  }
  for (int idx = t; idx < 32 * 16; idx += 256) {
    int r = idx >> 4, c4 = (idx & 15) << 2;
    float4 qv = *(const float4*)(Q + (size_t)(b * S_LEN + i0 + r) * DMODEL + h * DHEAD + c4);
    *(float4*)&Qs[r][c4] = qv;
  }
  __syncthreads();
  const int w = t >> 6, lane = t & 63;
  const float scale = 0.125f;     // 64^-0.5
  const float vsum_d = VS[(b * NHEADS + h) * DHEAD + lane];
  for (int qq = 0; qq < 8; ++qq) {
    const int i = i0 + w * 8 + qq;
    const int wlo = max(0, i - WIN), whi = min(S_LEN, i + WIN);
    const int rlo = wlo - jlo;
    const int nwin = whi - wlo;   // 64..128, slot0 always valid
    const int qrow = i - i0;
    const int r0 = rlo + lane;
    const bool has1 = (64 + lane) < nwin;
    const int r1 = has1 ? (r0 + 64) : r0;
    float acc0 = 0.f, acc1 = 0.f;
#pragma unroll 16
    for (int d = 0; d < DHEAD; ++d) {
      float qd = Qs[qrow][d];
      acc0 += qd * Ks[r0][d];
      acc1 += qd * Ks[r1][d];
    }
    float s0 = acc0 * scale;
    float s1 = has1 ? acc1 * scale : -1e30f;
    float mm = fmaxf(s0, s1);
#pragma unroll
    for (int off = 32; off; off >>= 1) mm = fmaxf(mm, __shfl_xor(mm, off));
    const float m = fmaxf(mm, 0.0f);    // out-of-window zeros participate in softmax max
    float p0 = __expf(s0 - m);
    float p1 = has1 ? __expf(s1 - m) : 0.0f;
    float ps = p0 + p1;
#pragma unroll
    for (int off = 32; off; off >>= 1) ps += __shfl_xor(ps, off);
    const float em = __expf(-m);
    const float denom = ps + (float)(S_LEN - nwin) * em;   // zero-score mass
    probs[w][lane] = p0;
    probs[w][64 + lane] = p1;
    // PV: lane = head dim
    float acc = 0.f, wacc = 0.f;
    const float* vb = V + (size_t)(b * S_LEN + wlo) * DMODEL + h * DHEAD + lane;
#pragma unroll 4
    for (int r = 0; r < nwin; ++r) {
      float p = probs[w][r];
      float vv = vb[(size_t)r * DMODEL];
      acc += p * vv;
      wacc += vv;
    }
    O[(size_t)(b * S_LEN + i) * DMODEL + h * DHEAD + lane] =
        (acc + em * (vsum_d - wacc)) / denom;
  }
}

// ---------------- layernorm over D=512, one block per row ----------------
__global__ void ln_kernel(const float* __restrict__ X, const float* __restrict__ g,
                          const float* __restrict__ be, float* __restrict__ Y) {
  int row = blockIdx.x;
  int t = threadIdx.x;            // 256 threads, 2 elems each
  const float* x = X + (size_t)row * DMODEL;
  float2 v = *(const float2*)(x + 2 * t);
  float s = v.x + v.y;
  float sq = v.x * v.x + v.y * v.y;
#pragma unroll
  for (int off = 32; off; off >>= 1) {
    s += __shfl_xor(s, off);
    sq += __shfl_xor(sq, off);
  }
  __shared__ float ss[4], sqq[4];
  int w = t >> 6, lane = t & 63;
  if (lane == 0) { ss[w] = s; sqq[w] = sq; }
  __syncthreads();
  s = ss[0] + ss[1] + ss[2] + ss[3];
  sq = sqq[0] + sqq[1] + sqq[2] + sqq[3];
  float mu = s * (1.0f / DMODEL);
  float var = sq * (1.0f / DMODEL) - mu * mu;
  float rstd = rsqrtf(var + 1e-5f);
  float g0 = g[2 * t], g1 = g[2 * t + 1];
  float b0 = be[2 * t], b1 = be[2 * t + 1];
  float2 o;
  o.x = (v.x - mu) * rstd * g0 + b0;
  o.y = (v.y - mu) * rstd * g1 + b1;
  *(float2*)(Y + (size_t)row * DMODEL + 2 * t) = o;
}

// ---------------- final projection: out[b,c] = X[b,:] . Wo[c,:] + ob[c] ----------------
__global__ void outproj_partial_kernel(const float* __restrict__ X, const float* __restrict__ Wo,
                                       float* __restrict__ part) {
  const int KTOT = S_LEN * DMODEL;   // 524288
  const int CH = KTOT / 16;          // 32768
  int chunk = blockIdx.x, c = blockIdx.y, b = blockIdx.z;
  const float* x = X + (size_t)b * KTOT + (size_t)chunk * CH;
  const float* wv = Wo + (size_t)c * KTOT + (size_t)chunk * CH;
  float acc = 0.f;
  for (int i = threadIdx.x * 4; i < CH; i += 256 * 4) {
    float4 a = *(const float4*)(x + i);
    float4 w4 = *(const float4*)(wv + i);
    acc += a.x * w4.x + a.y * w4.y + a.z * w4.z + a.w * w4.w;
  }
#pragma unroll
  for (int off = 32; off; off >>= 1) acc += __shfl_xor(acc, off);
  __shared__ float red[4];
  int w = threadIdx.x >> 6, lane = threadIdx.x & 63;
  if (lane == 0) red[w] = acc;
  __syncthreads();
  if (threadIdx.x == 0)
    part[(b * 6 + c) * 16 + chunk] = red[0] + red[1] + red[2] + red[3];
}

__global__ void outproj_final_kernel(const float* __restrict__ part, const float* __restrict__ ob,
                                     float* __restrict__ out) {
  int idx = threadIdx.x;
  if (idx < 48) {
    float s = 0.f;
#pragma unroll
    for (int k = 0; k < 16; ++k) s += part[idx * 16 + k];
    out[idx] = s + ob[idx % 6];
  }
}

extern "C" void kernel_launch(void* const* d_in, const int* in_sizes, int n_in,
                              void* d_out, int out_size, void* d_ws, size_t ws_size,
                              hipStream_t stream) {
  (void)in_sizes; (void)n_in; (void)out_size; (void)ws_size;
  const int*   inputs = (const int*)  d_in[0];
  const float* emb    = (const float*)d_in[1];
  const float* wq     = (const float*)d_in[2];
  const float* bq     = (const float*)d_in[3];
  const float* wk     = (const float*)d_in[4];
  const float* bk     = (const float*)d_in[5];
  const float* wv     = (const float*)d_in[6];
  const float* bv     = (const float*)d_in[7];
  const float* ln_g   = (const float*)d_in[8];
  const float* ln_b   = (const float*)d_in[9];
  const float* fc1_w  = (const float*)d_in[10];
  const float* fc1_b  = (const float*)d_in[11];
  const float* fc2_w  = (const float*)d_in[12];
  const float* fc2_b  = (const float*)d_in[13];
  const float* out_w  = (const float*)d_in[14];
  const float* out_b  = (const float*)d_in[15];
  float* out = (float*)d_out;

  const size_t BUF = (size_t)8192 * 512 * 4;   // 16 MiB per activation buffer
  char* ws = (char*)d_ws;
  float* X  = (float*)(ws + 0 * BUF);
  float* Qb = (float*)(ws + 1 * BUF);
  float* Kb = (float*)(ws + 2 * BUF);
  float* Vb = (float*)(ws + 3 * BUF);
  float* Ab = (float*)(ws + 4 * BUF);
  float* XB = (float*)(ws + 5 * BUF);
  float* Hb = Qb;                              // H (8192x2048) reuses Q..A region exactly
  float* VS = (float*)(ws + 6 * BUF);          // 64*64 floats
  float* part = VS + 64 * 64;                  // 768 floats

  const int M = 8192;
  embed_pe_kernel<<<8192, 256, 0, stream>>>(inputs, emb, X);
  for (int it = 0; it < 6; ++it) {
    gemm_kernel<0><<<dim3(128, 8), 256, 0, stream>>>(X, wq, bq, nullptr, Qb, M, 512, 512);
    gemm_kernel<0><<<dim3(128, 8), 256, 0, stream>>>(X, wk, bk, nullptr, Kb, M, 512, 512);
    gemm_kernel<0><<<dim3(128, 8), 256, 0, stream>>>(X, wv, bv, nullptr, Vb, M, 512, 512);
    vsum_kernel<<<64, 64, 0, stream>>>(Vb, VS);
    attn_kernel<<<dim3(32, 8, 8), 256, 0, stream>>>(Qb, Kb, Vb, VS, Ab);
    ln_kernel<<<8192, 256, 0, stream>>>(Ab, ln_g, ln_b, XB);
    gemm_kernel<1><<<dim3(128, 32), 256, 0, stream>>>(XB, fc1_w, fc1_b, nullptr, Hb, M, 2048, 512);
    gemm_kernel<0><<<dim3(128, 8), 256, 0, stream>>>(Hb, fc2_w, fc2_b, XB, X, M, 512, 2048);
    ln_kernel<<<8192, 256, 0, stream>>>(X, ln_g, ln_b, X);
  }
  outproj_partial_kernel<<<dim3(16, 6, 8), 256, 0, stream>>>(X, out_w, part);
  outproj_final_kernel<<<1, 64, 0, stream>>>(part, out_b, out);
}

// Round 2
// 2413.106 us; speedup vs baseline: 2.6354x; 2.6354x over previous
//
#include <hip/hip_runtime.h>

#define S_LEN 1024
#define DMODEL 512
#define NHEADS 8
#define DHEAD 64
#define HDIM 2048
#define WIN 64

typedef _Float16 f16x8 __attribute__((ext_vector_type(8)));
typedef _Float16 f16x2 __attribute__((ext_vector_type(2)));
typedef float f32x4 __attribute__((ext_vector_type(4)));

__device__ __forceinline__ void stage16(const _Float16* g, _Float16* l) {
  __builtin_amdgcn_global_load_lds((const __attribute__((address_space(1))) unsigned int*)g,
                                   (__attribute__((address_space(3))) unsigned int*)l, 16, 0, 0);
}

// ---------------- weight prep: f32 -> f16, QKV concat ----------------
__global__ void wprep_kernel(const float* __restrict__ wq, const float* __restrict__ wk,
                             const float* __restrict__ wv, const float* __restrict__ bq,
                             const float* __restrict__ bk, const float* __restrict__ bv,
                             const float* __restrict__ w1, const float* __restrict__ w2,
                             _Float16* __restrict__ Wqkv, float* __restrict__ bqkv,
                             _Float16* __restrict__ W1h, _Float16* __restrict__ W2h) {
  int i = blockIdx.x * 256 + threadIdx.x;
  if (i < 262144) {
    Wqkv[i]          = (_Float16)wq[i];
    Wqkv[262144 + i] = (_Float16)wk[i];
    Wqkv[524288 + i] = (_Float16)wv[i];
  }
  if (i < 1048576) {
    W1h[i] = (_Float16)w1[i];
    W2h[i] = (_Float16)w2[i];
  }
  if (i < 512) { bqkv[i] = bq[i]; bqkv[512 + i] = bk[i]; bqkv[1024 + i] = bv[i]; }
}

// ---------------- embed + positional encoding (f32 + f16 copies) ----------------
__global__ void embed_pe_kernel(const int* __restrict__ inputs, const float* __restrict__ emb,
                                float* __restrict__ X, _Float16* __restrict__ Xb) {
  int row = blockIdx.x;          // b*S + s
  int s = row & (S_LEN - 1);
  int t = threadIdx.x;           // pair index 0..255
  int tok = inputs[row];
  float dv = __expf(-logf(10000.0f) * (2.0f * (float)t) / (float)DMODEL);
  float ang = (float)s * dv;
  float sv = sinf(ang);
  float cv = cosf(ang);
  size_t base = (size_t)row * DMODEL + 2 * t;
  float x0 = emb[(size_t)tok * DMODEL + 2 * t] + sv;
  float x1 = emb[(size_t)tok * DMODEL + 2 * t + 1] + cv;
  X[base] = x0; X[base + 1] = x1;
  f16x2 h; h[0] = (_Float16)x0; h[1] = (_Float16)x1;
  *(f16x2*)(Xb + base) = h;
}

// ---------------- MFMA f16 GEMM: C = A @ W^T + bias (+res / +relu->f16) --------
// A[M,K] f16, W[N,K] f16 row-major. 128x128 tile, BK=32, 256 threads (4 waves 2x2),
// per wave 4x4 frags of 16x16x32. m97 structure: global_load_lds(16B) staging.
#define EPI_PLAIN 0
#define EPI_RELU16 1
#define EPI_RES 2

template <int EPI>
__launch_bounds__(256)
__global__ void mfma_gemm(const _Float16* __restrict__ A, const _Float16* __restrict__ W,
                          const float* __restrict__ bias, const float* __restrict__ res,
                          float* __restrict__ Cf, _Float16* __restrict__ Ch,
                          int M, int N, int K) {
  __shared__ _Float16 As[128 * 32];
  __shared__ _Float16 Bs[128 * 32];
  const int bm = blockIdx.x * 128;
  const int bn = blockIdx.y * 128;
  const int t = threadIdx.x;
  const int lane = t & 63;
  const int w = t >> 6;
  const int wr = w >> 1, wc = w & 1;
  const int l15 = lane & 15, l4 = lane >> 4;

  // staging: idx in [0,512), row = idx>>2, kgroup = (idx&3)*8; LDS byte off = idx*16
  const int idx0 = t, idx1 = t + 256;
  const int r0 = idx0 >> 2, kg0 = (idx0 & 3) << 3;
  const int r1 = idx1 >> 2, kg1 = (idx1 & 3) << 3;
  const _Float16* Ag0 = A + (size_t)(bm + r0) * K + kg0;
  const _Float16* Ag1 = A + (size_t)(bm + r1) * K + kg1;
  const _Float16* Wg0 = W + (size_t)(bn + r0) * K + kg0;
  const _Float16* Wg1 = W + (size_t)(bn + r1) * K + kg1;
  _Float16* Al0 = As + idx0 * 8;
  _Float16* Al1 = As + idx1 * 8;
  _Float16* Bl0 = Bs + idx0 * 8;
  _Float16* Bl1 = Bs + idx1 * 8;

  f32x4 acc[4][4] = {};
  for (int k0 = 0; k0 < K; k0 += 32) {
    stage16(Ag0 + k0, Al0);
    stage16(Ag1 + k0, Al1);
    stage16(Wg0 + k0, Bl0);
    stage16(Wg1 + k0, Bl1);
    __syncthreads();              // drains vmcnt: LDS tiles ready
    f16x8 af[4], bf[4];
#pragma unroll
    for (int m = 0; m < 4; ++m)
      af[m] = *(const f16x8*)&As[(wr * 64 + m * 16 + l15) * 32 + l4 * 8];
#pragma unroll
    for (int n = 0; n < 4; ++n)
      bf[n] = *(const f16x8*)&Bs[(wc * 64 + n * 16 + l15) * 32 + l4 * 8];
#pragma unroll
    for (int m = 0; m < 4; ++m)
#pragma unroll
      for (int n = 0; n < 4; ++n)
        acc[m][n] = __builtin_amdgcn_mfma_f32_16x16x32_f16(af[m], bf[n], acc[m][n], 0, 0, 0);
    __syncthreads();              // all reads done before next stage overwrites
  }
  // epilogue: D row = bm+wr*64+m*16+l4*4+j ; col = bn+wc*64+n*16+l15
#pragma unroll
  for (int m = 0; m < 4; ++m) {
    int row = bm + wr * 64 + m * 16 + l4 * 4;
#pragma unroll
    for (int n = 0; n < 4; ++n) {
      int col = bn + wc * 64 + n * 16 + l15;
      float bb = bias[col];
#pragma unroll
      for (int j = 0; j < 4; ++j) {
        float v = acc[m][n][j] + bb;
        if (EPI == EPI_RELU16) {
          v = fmaxf(v, 0.0f);
          Ch[(size_t)(row + j) * N + col] = (_Float16)v;
        } else if (EPI == EPI_RES) {
          Cf[(size_t)(row + j) * N + col] = v + res[(size_t)(row + j) * N + col];
        } else {
          Cf[(size_t)(row + j) * N + col] = v;
        }
      }
    }
  }
}

// ---------------- V column sums (full-softmax zero-correction) ----------------
__global__ void vs_zero_kernel(float* __restrict__ VS) {
  VS[blockIdx.x * 256 + threadIdx.x] = 0.0f;
}
// grid (8 chunks, 8 b), 512 threads; V lives at col 1024+ of QKV (stride 1536)
__global__ void vsum_kernel(const float* __restrict__ QKV, float* __restrict__ VS) {
  int c = threadIdx.x;                 // 0..511 = h*64+d
  int chunk = blockIdx.x, b = blockIdx.y;
  const float* base = QKV + ((size_t)(b * S_LEN + chunk * 128)) * 1536 + 1024 + c;
  float acc = 0.f;
  for (int i = 0; i < 128; ++i) acc += base[(size_t)i * 1536];
  atomicAdd(&VS[b * 512 + c], acc);
}

// ---------------- windowed attention, full-softmax zero correction ----------------
// grid (S/32, H, B), 256 threads = 4 waves, 8 queries per wave. QKV fused stride 1536.
__launch_bounds__(256)
__global__ void attn_kernel(const float* __restrict__ QKV, const float* __restrict__ VS,
                            float* __restrict__ O) {
  __shared__ float Ks[160][65];
  __shared__ float Qs[32][64];
  __shared__ float probs[4][128];
  const int qt = blockIdx.x, h = blockIdx.y, b = blockIdx.z;
  const int i0 = qt * 32;
  const int jlo = max(0, i0 - WIN);
  const int jhi = min(S_LEN, i0 + 31 + WIN + 1);
  const int nst = jhi - jlo;      // <= 159
  const int t = threadIdx.x;
  for (int idx = t; idx < nst * 16; idx += 256) {
    int r = idx >> 4, c4 = (idx & 15) << 2;
    float4 kv = *(const float4*)(QKV + (size_t)(b * S_LEN + jlo + r) * 1536 + 512 + h * DHEAD + c4);
    Ks[r][c4 + 0] = kv.x; Ks[r][c4 + 1] = kv.y; Ks[r][c4 + 2] = kv.z; Ks[r][c4 + 3] = kv.w;
  }
  for (int idx = t; idx < 32 * 16; idx += 256) {
    int r = idx >> 4, c4 = (idx & 15) << 2;
    float4 qv = *(const float4*)(QKV + (size_t)(b * S_LEN + i0 + r) * 1536 + h * DHEAD + c4);
    *(float4*)&Qs[r][c4] = qv;
  }
  __syncthreads();
  const int w = t >> 6, lane = t & 63;
  const float scale = 0.125f;     // 64^-0.5
  const float vsum_d = VS[b * 512 + h * DHEAD + lane];
  for (int qq = 0; qq < 8; ++qq) {
    const int i = i0 + w * 8 + qq;
    const int wlo = max(0, i - WIN), whi = min(S_LEN, i + WIN);
    const int rlo = wlo - jlo;
    const int nwin = whi - wlo;   // 64..128, slot0 always valid
    const int qrow = i - i0;
    const int r0 = rlo + lane;
    const bool has1 = (64 + lane) < nwin;
    const int r1 = has1 ? (r0 + 64) : r0;
    float acc0 = 0.f, acc1 = 0.f;
#pragma unroll 16
    for (int d = 0; d < DHEAD; ++d) {
      float qd = Qs[qrow][d];
      acc0 += qd * Ks[r0][d];
      acc1 += qd * Ks[r1][d];
    }
    float s0 = acc0 * scale;
    float s1 = has1 ? acc1 * scale : -1e30f;
    float mm = fmaxf(s0, s1);
#pragma unroll
    for (int off = 32; off; off >>= 1) mm = fmaxf(mm, __shfl_xor(mm, off));
    const float m = fmaxf(mm, 0.0f);    // zero scores participate in softmax max
    float p0 = __expf(s0 - m);
    float p1 = has1 ? __expf(s1 - m) : 0.0f;
    float ps = p0 + p1;
#pragma unroll
    for (int off = 32; off; off >>= 1) ps += __shfl_xor(ps, off);
    const float em = __expf(-m);
    const float denom = ps + (float)(S_LEN - nwin) * em;   // zero-score mass
    probs[w][lane] = p0;
    probs[w][64 + lane] = p1;
    // PV: lane = head dim
    float acc = 0.f, wacc = 0.f;
    const float* vb = QKV + (size_t)(b * S_LEN + wlo) * 1536 + 1024 + h * DHEAD + lane;
#pragma unroll 4
    for (int r = 0; r < nwin; ++r) {
      float p = probs[w][r];
      float vv = vb[(size_t)r * 1536];
      acc += p * vv;
      wacc += vv;
    }
    O[(size_t)(b * S_LEN + i) * DMODEL + h * DHEAD + lane] =
        (acc + em * (vsum_d - wacc)) / denom;
  }
}

// ---------------- layernorm over D=512; writes f32 + f16 ----------------
__global__ void ln_kernel(const float* __restrict__ X, const float* __restrict__ g,
                          const float* __restrict__ be, float* __restrict__ Y,
                          _Float16* __restrict__ Yh) {
  int row = blockIdx.x;
  int t = threadIdx.x;            // 256 threads, 2 elems each
  const float* x = X + (size_t)row * DMODEL;
  float2 v = *(const float2*)(x + 2 * t);
  float s = v.x + v.y;
  float sq = v.x * v.x + v.y * v.y;
#pragma unroll
  for (int off = 32; off; off >>= 1) {
    s += __shfl_xor(s, off);
    sq += __shfl_xor(sq, off);
  }
  __shared__ float ss[4], sqq[4];
  int w = t >> 6, lane = t & 63;
  if (lane == 0) { ss[w] = s; sqq[w] = sq; }
  __syncthreads();
  s = ss[0] + ss[1] + ss[2] + ss[3];
  sq = sqq[0] + sqq[1] + sqq[2] + sqq[3];
  float mu = s * (1.0f / DMODEL);
  float var = sq * (1.0f / DMODEL) - mu * mu;
  float rstd = rsqrtf(var + 1e-5f);
  float g0 = g[2 * t], g1 = g[2 * t + 1];
  float b0 = be[2 * t], b1 = be[2 * t + 1];
  float2 o;
  o.x = (v.x - mu) * rstd * g0 + b0;
  o.y = (v.y - mu) * rstd * g1 + b1;
  *(float2*)(Y + (size_t)row * DMODEL + 2 * t) = o;
  f16x2 hh; hh[0] = (_Float16)o.x; hh[1] = (_Float16)o.y;
  *(f16x2*)(Yh + (size_t)row * DMODEL + 2 * t) = hh;
}

// ---------------- final projection ----------------
__global__ void outproj_partial_kernel(const float* __restrict__ X, const float* __restrict__ Wo,
                                       float* __restrict__ part) {
  const int KTOT = S_LEN * DMODEL;   // 524288
  const int CH = KTOT / 16;          // 32768
  int chunk = blockIdx.x, c = blockIdx.y, b = blockIdx.z;
  const float* x = X + (size_t)b * KTOT + (size_t)chunk * CH;
  const float* wv = Wo + (size_t)c * KTOT + (size_t)chunk * CH;
  float acc = 0.f;
  for (int i = threadIdx.x * 4; i < CH; i += 256 * 4) {
    float4 a = *(const float4*)(x + i);
    float4 w4 = *(const float4*)(wv + i);
    acc += a.x * w4.x + a.y * w4.y + a.z * w4.z + a.w * w4.w;
  }
#pragma unroll
  for (int off = 32; off; off >>= 1) acc += __shfl_xor(acc, off);
  __shared__ float red[4];
  int w = threadIdx.x >> 6, lane = threadIdx.x & 63;
  if (lane == 0) red[w] = acc;
  __syncthreads();
  if (threadIdx.x == 0)
    part[(b * 6 + c) * 16 + chunk] = red[0] + red[1] + red[2] + red[3];
}

__global__ void outproj_final_kernel(const float* __restrict__ part, const float* __restrict__ ob,
                                     float* __restrict__ out) {
  int idx = threadIdx.x;
  if (idx < 48) {
    float s = 0.f;
#pragma unroll
    for (int k = 0; k < 16; ++k) s += part[idx * 16 + k];
    out[idx] = s + ob[idx % 6];
  }
}

extern "C" void kernel_launch(void* const* d_in, const int* in_sizes, int n_in,
                              void* d_out, int out_size, void* d_ws, size_t ws_size,
                              hipStream_t stream) {
  (void)in_sizes; (void)n_in; (void)out_size; (void)ws_size;
  const int*   inputs = (const int*)  d_in[0];
  const float* emb    = (const float*)d_in[1];
  const float* wq     = (const float*)d_in[2];
  const float* bq     = (const float*)d_in[3];
  const float* wk     = (const float*)d_in[4];
  const float* bk     = (const float*)d_in[5];
  const float* wv     = (const float*)d_in[6];
  const float* bv     = (const float*)d_in[7];
  const float* ln_g   = (const float*)d_in[8];
  const float* ln_b   = (const float*)d_in[9];
  const float* fc1_w  = (const float*)d_in[10];
  const float* fc1_b  = (const float*)d_in[11];
  const float* fc2_w  = (const float*)d_in[12];
  const float* fc2_b  = (const float*)d_in[13];
  const float* out_w  = (const float*)d_in[14];
  const float* out_b  = (const float*)d_in[15];
  float* out = (float*)d_out;

  const int M = 8192;
  char* p = (char*)d_ws;
  float*    X    = (float*)p;      p += (size_t)M * 512 * 4;      // 16 MB
  _Float16* Xb   = (_Float16*)p;   p += (size_t)M * 512 * 2;      //  8 MB
  float*    QKV  = (float*)p;      p += (size_t)M * 1536 * 4;     // 48 MB
  float*    XB   = (float*)p;      p += (size_t)M * 512 * 4;      // 16 MB
  _Float16* XBb  = (_Float16*)p;   p += (size_t)M * 512 * 2;      //  8 MB
  _Float16* H    = (_Float16*)p;   p += (size_t)M * 2048 * 2;     // 32 MB
  float*    Ab   = (float*)H;                                     // aliases H (dead by FC1)
  _Float16* Wqkv = (_Float16*)p;   p += (size_t)1536 * 512 * 2;
  _Float16* W1h  = (_Float16*)p;   p += (size_t)2048 * 512 * 2;
  _Float16* W2h  = (_Float16*)p;   p += (size_t)512 * 2048 * 2;
  float*    bqkv = (float*)p;      p += 1536 * 4;
  float*    VS   = (float*)p;      p += 4096 * 4;
  float*    part = (float*)p;      p += 768 * 4;

  wprep_kernel<<<4096, 256, 0, stream>>>(wq, wk, wv, bq, bk, bv, fc1_w, fc2_w,
                                         Wqkv, bqkv, W1h, W2h);
  embed_pe_kernel<<<8192, 256, 0, stream>>>(inputs, emb, X, Xb);
  for (int it = 0; it < 6; ++it) {
    mfma_gemm<EPI_PLAIN><<<dim3(64, 12), 256, 0, stream>>>(Xb, Wqkv, bqkv, nullptr,
                                                           QKV, nullptr, M, 1536, 512);
    vs_zero_kernel<<<16, 256, 0, stream>>>(VS);
    vsum_kernel<<<dim3(8, 8), 512, 0, stream>>>(QKV, VS);
    attn_kernel<<<dim3(32, 8, 8), 256, 0, stream>>>(QKV, VS, Ab);
    ln_kernel<<<8192, 256, 0, stream>>>(Ab, ln_g, ln_b, XB, XBb);
    mfma_gemm<EPI_RELU16><<<dim3(64, 16), 256, 0, stream>>>(XBb, W1h, fc1_b, nullptr,
                                                            nullptr, H, M, 2048, 512);
    mfma_gemm<EPI_RES><<<dim3(64, 4), 256, 0, stream>>>(H, W2h, fc2_b, XB,
                                                        X, nullptr, M, 512, 2048);
    ln_kernel<<<8192, 256, 0, stream>>>(X, ln_g, ln_b, X, Xb);
  }
  outproj_partial_kernel<<<dim3(16, 6, 8), 256, 0, stream>>>(X, out_w, part);
  outproj_final_kernel<<<1, 64, 0, stream>>>(part, out_b, out);
}

// Round 3
// 891.351 us; speedup vs baseline: 7.1347x; 2.7072x over previous
//
#include <hip/hip_runtime.h>

#define S_LEN 1024
#define DMODEL 512
#define NHEADS 8
#define DHEAD 64
#define HDIM 2048
#define WIN 64

typedef _Float16 f16x8 __attribute__((ext_vector_type(8)));
typedef _Float16 f16x2 __attribute__((ext_vector_type(2)));
typedef float f32x4 __attribute__((ext_vector_type(4)));
typedef float f32x16 __attribute__((ext_vector_type(16)));

__device__ __forceinline__ void stage16(const _Float16* g, _Float16* l) {
  __builtin_amdgcn_global_load_lds((const __attribute__((address_space(1))) unsigned int*)g,
                                   (__attribute__((address_space(3))) unsigned int*)l, 16, 0, 0);
}

// ---------------- weight prep: f32 -> f16, QKV concat ----------------
__global__ void wprep_kernel(const float* __restrict__ wq, const float* __restrict__ wk,
                             const float* __restrict__ wv, const float* __restrict__ bq,
                             const float* __restrict__ bk, const float* __restrict__ bv,
                             const float* __restrict__ w1, const float* __restrict__ w2,
                             _Float16* __restrict__ Wqkv, float* __restrict__ bqkv,
                             _Float16* __restrict__ W1h, _Float16* __restrict__ W2h) {
  int i = blockIdx.x * 256 + threadIdx.x;
  if (i < 262144) {
    Wqkv[i]          = (_Float16)wq[i];
    Wqkv[262144 + i] = (_Float16)wk[i];
    Wqkv[524288 + i] = (_Float16)wv[i];
  }
  if (i < 1048576) {
    W1h[i] = (_Float16)w1[i];
    W2h[i] = (_Float16)w2[i];
  }
  if (i < 512) { bqkv[i] = bq[i]; bqkv[512 + i] = bk[i]; bqkv[1024 + i] = bv[i]; }
}

// ---------------- embed + positional encoding (f32 + f16 copies) ----------------
__global__ void embed_pe_kernel(const int* __restrict__ inputs, const float* __restrict__ emb,
                                float* __restrict__ X, _Float16* __restrict__ Xb) {
  int row = blockIdx.x;          // b*S + s
  int s = row & (S_LEN - 1);
  int t = threadIdx.x;           // pair index 0..255
  int tok = inputs[row];
  float dv = __expf(-logf(10000.0f) * (2.0f * (float)t) / (float)DMODEL);
  float ang = (float)s * dv;
  float sv = sinf(ang);
  float cv = cosf(ang);
  size_t base = (size_t)row * DMODEL + 2 * t;
  float x0 = emb[(size_t)tok * DMODEL + 2 * t] + sv;
  float x1 = emb[(size_t)tok * DMODEL + 2 * t + 1] + cv;
  X[base] = x0; X[base + 1] = x1;
  f16x2 h; h[0] = (_Float16)x0; h[1] = (_Float16)x1;
  *(f16x2*)(Xb + base) = h;
}

// ---------------- MFMA f16 GEMM: C = A @ W^T + bias ----------------
// EPI: 0 plain f32, 1 relu->f16, 2 +res->f32, 3 plain->f16
#define EPI_PLAIN 0
#define EPI_RELU16 1
#define EPI_RES 2
#define EPI_F16 3

template <int EPI>
__launch_bounds__(256)
__global__ void mfma_gemm(const _Float16* __restrict__ A, const _Float16* __restrict__ W,
                          const float* __restrict__ bias, const float* __restrict__ res,
                          float* __restrict__ Cf, _Float16* __restrict__ Ch,
                          int M, int N, int K) {
  __shared__ _Float16 As[128 * 32];
  __shared__ _Float16 Bs[128 * 32];
  const int bm = blockIdx.x * 128;
  const int bn = blockIdx.y * 128;
  const int t = threadIdx.x;
  const int lane = t & 63;
  const int w = t >> 6;
  const int wr = w >> 1, wc = w & 1;
  const int l15 = lane & 15, l4 = lane >> 4;

  const int idx0 = t, idx1 = t + 256;
  const int r0 = idx0 >> 2, kg0 = (idx0 & 3) << 3;
  const int r1 = idx1 >> 2, kg1 = (idx1 & 3) << 3;
  const _Float16* Ag0 = A + (size_t)(bm + r0) * K + kg0;
  const _Float16* Ag1 = A + (size_t)(bm + r1) * K + kg1;
  const _Float16* Wg0 = W + (size_t)(bn + r0) * K + kg0;
  const _Float16* Wg1 = W + (size_t)(bn + r1) * K + kg1;
  _Float16* Al0 = As + idx0 * 8;
  _Float16* Al1 = As + idx1 * 8;
  _Float16* Bl0 = Bs + idx0 * 8;
  _Float16* Bl1 = Bs + idx1 * 8;

  f32x4 acc[4][4] = {};
  for (int k0 = 0; k0 < K; k0 += 32) {
    stage16(Ag0 + k0, Al0);
    stage16(Ag1 + k0, Al1);
    stage16(Wg0 + k0, Bl0);
    stage16(Wg1 + k0, Bl1);
    __syncthreads();
    f16x8 af[4], bf[4];
#pragma unroll
    for (int m = 0; m < 4; ++m)
      af[m] = *(const f16x8*)&As[(wr * 64 + m * 16 + l15) * 32 + l4 * 8];
#pragma unroll
    for (int n = 0; n < 4; ++n)
      bf[n] = *(const f16x8*)&Bs[(wc * 64 + n * 16 + l15) * 32 + l4 * 8];
#pragma unroll
    for (int m = 0; m < 4; ++m)
#pragma unroll
      for (int n = 0; n < 4; ++n)
        acc[m][n] = __builtin_amdgcn_mfma_f32_16x16x32_f16(af[m], bf[n], acc[m][n], 0, 0, 0);
    __syncthreads();
  }
#pragma unroll
  for (int m = 0; m < 4; ++m) {
    int row = bm + wr * 64 + m * 16 + l4 * 4;
#pragma unroll
    for (int n = 0; n < 4; ++n) {
      int col = bn + wc * 64 + n * 16 + l15;
      float bb = bias[col];
#pragma unroll
      for (int j = 0; j < 4; ++j) {
        float v = acc[m][n][j] + bb;
        if (EPI == EPI_RELU16) {
          v = fmaxf(v, 0.0f);
          Ch[(size_t)(row + j) * N + col] = (_Float16)v;
        } else if (EPI == EPI_F16) {
          Ch[(size_t)(row + j) * N + col] = (_Float16)v;
        } else if (EPI == EPI_RES) {
          Cf[(size_t)(row + j) * N + col] = v + res[(size_t)(row + j) * N + col];
        } else {
          Cf[(size_t)(row + j) * N + col] = v;
        }
      }
    }
  }
}

// ---------------- V column sums (full-softmax zero-correction) ----------------
__global__ void vs_zero_kernel(float* __restrict__ VS) {
  VS[blockIdx.x * 256 + threadIdx.x] = 0.0f;
}
__global__ void vsum_kernel(const _Float16* __restrict__ QKVh, float* __restrict__ VS) {
  int c = threadIdx.x;                 // 0..511 = h*64+d
  int chunk = blockIdx.x, b = blockIdx.y;
  const _Float16* base = QKVh + ((size_t)(b * S_LEN + chunk * 128)) * 1536 + 1024 + c;
  float acc = 0.f;
  for (int i = 0; i < 128; ++i) acc += (float)base[(size_t)i * 1536];
  atomicAdd(&VS[b * 512 + c], acc);
}

// ---------------- MFMA windowed attention, full-softmax zero correction --------
// grid (S/128, H, B) = (8,8,8); 256 threads = 4 waves, 32 queries per wave.
// QKV f16 fused stride 1536 (Q at 0, K at 512, V at 1024).
#define KTMAX 256
#define VTS 264   // Vt row stride (f16), 16B-aligned

__launch_bounds__(256)
__global__ void attn_kernel(const _Float16* __restrict__ QKVh, const float* __restrict__ VSg,
                            float* __restrict__ O) {
  __shared__ _Float16 Ks[KTMAX * 64];      // row-major, XOR-swizzled cols, 32KB
  __shared__ _Float16 Vt[64 * VTS];        // transposed V, 33KB
  __shared__ float VsC[8][64];             // per-32-key-chunk V column sums

  const int qb0 = blockIdx.x * 128, h = blockIdx.y, b = blockIdx.z;
  const int jlo = max(0, qb0 - WIN);
  const int jhi = min(S_LEN, qb0 + 128 + WIN);
  const int KT = jhi - jlo;                 // 192 or 256, multiple of 32
  const int t = threadIdx.x;
  const int lane = t & 63, w = t >> 6;
  const int hi = lane >> 5, l31 = lane & 31;

  // ---- stage K (global_load_lds, source pre-swizzled: rule #21)
  const _Float16* Kg = QKVh + ((size_t)(b * S_LEN + jlo)) * 1536 + 512 + h * 64;
#pragma unroll
  for (int p = 0; p < 8; ++p) {
    int u = t + p * 256;                    // 0..2047
    int row = u >> 3;
    int cb = (u & 7) * 16;                  // byte col within 128B row
    int rowc = min(row, KT - 1);
    int scb = cb ^ ((row & 7) << 4);
    stage16(Kg + (size_t)rowc * 1536 + (scb >> 1), Ks + u * 8);
  }
  // ---- stage Vt (transposed, reg path), zero-fill rows >= KT
  const _Float16* Vg = QKVh + ((size_t)(b * S_LEN + jlo)) * 1536 + 1024 + h * 64;
#pragma unroll
  for (int p = 0; p < 8; ++p) {
    int u = t + p * 256;
    int row = u >> 3;                       // key 0..255
    int d0 = (u & 7) * 8;
    f16x8 v = {0, 0, 0, 0, 0, 0, 0, 0};
    if (row < KT) v = *(const f16x8*)(Vg + (size_t)row * 1536 + d0);
#pragma unroll
    for (int e = 0; e < 8; ++e) Vt[(d0 + e) * VTS + row] = v[e];
  }
  __syncthreads();
  // ---- per-chunk V column sums
  for (int slot = t; slot < 512; slot += 256) {
    int c = slot >> 6, d = slot & 63;
    const f16x8* col = (const f16x8*)(Vt + d * VTS + c * 32);
    float s = 0.f;
#pragma unroll
    for (int g = 0; g < 4; ++g) {
      f16x8 v = col[g];
#pragma unroll
      for (int e = 0; e < 8; ++e) s += (float)v[e];
    }
    VsC[c][d] = s;
  }
  // ---- Q fragments (kept in registers for whole kernel)
  const int qw = qb0 + w * 32;
  const _Float16* Qg = QKVh + ((size_t)(b * S_LEN + qw + l31)) * 1536 + h * 64;
  f16x8 qf[4];
#pragma unroll
  for (int ds = 0; ds < 4; ++ds) qf[ds] = *(const f16x8*)(Qg + ds * 16 + hi * 8);
  __syncthreads();

  // ---- wave's chunk range
  const int c0 = max(0, qw - WIN - jlo) >> 5;
  const int c1 = min(KT, qw + 96 - jlo) >> 5;   // exclusive
  const int nproc = (c1 - c0) * 32;
  const int i = qw + l31;                        // this lane's query (as column owner)
  const int wlo = i - WIN, whi = i + WIN;

  float m = 0.f, l = 0.f;                        // zeros always exist => m floor 0
  f32x16 accA = {}, accB = {};                   // O[q][d] halves: d=l31 / d=32+l31

  union PK { f16x2 h; unsigned u; };
  union A8 { unsigned u[4]; f16x8 h; };

  for (int c = c0; c < c1; ++c) {
    const int kb = c * 32;
    // QK^T (swapped): S^T[key][q], A=K rows, B=Q rows
    f32x16 sf = {};
#pragma unroll
    for (int ds = 0; ds < 4; ++ds) {
      int row = kb + l31;
      int cbyte = ((ds * 16 + hi * 8) * 2) ^ ((row & 7) << 4);
      f16x8 kf = *(const f16x8*)((const char*)Ks + row * 128 + cbyte);
      sf = __builtin_amdgcn_mfma_f32_32x32x16_f16(kf, qf[ds], sf, 0, 0, 0);
    }
    // mask (zero, not -inf) + scale; per-lane row max
    float s[16]; float pm = -1e30f;
#pragma unroll
    for (int r = 0; r < 16; ++r) {
      int gk = jlo + kb + (r & 3) + 8 * (r >> 2) + 4 * hi;
      float v = (gk >= wlo && gk < whi) ? sf[r] * 0.125f : 0.f;
      s[r] = v;
      pm = fmaxf(pm, v);
    }
    pm = fmaxf(pm, __shfl_xor(pm, 32));
    // defer-max (T13): rescale only when some row's max grew past m+8
    if (!__all(pm <= m + 8.f)) {
      float mn = fmaxf(m, pm);
      float f = __expf(m - mn);
      l *= f;
#pragma unroll
      for (int r = 0; r < 16; ++r) {
        int q = (r & 3) + 8 * (r >> 2) + 4 * hi;
        float fr = __shfl(f, q);
        accA[r] *= fr; accB[r] *= fr;
      }
      m = mn;
    }
    float p[16]; float ls = 0.f;
#pragma unroll
    for (int r = 0; r < 16; ++r) { p[r] = __expf(s[r] - m); ls += p[r]; }
    l += ls;                                    // half-sum; combined at epilogue
    // P -> f16 A-frags (keys (lane>>5)*8+e per 16-key k-step)
    unsigned u[8], x[8];
#pragma unroll
    for (int kk = 0; kk < 8; ++kk) {
      PK cv; cv.h[0] = (_Float16)p[2 * kk]; cv.h[1] = (_Float16)p[2 * kk + 1];
      u[kk] = cv.u;
    }
#pragma unroll
    for (int kk = 0; kk < 8; ++kk) x[kk] = (unsigned)__shfl_xor((int)u[kk], 32);
    A8 a0, a1;
    a0.u[0] = hi ? x[2] : u[0]; a0.u[1] = hi ? x[3] : u[1];
    a0.u[2] = hi ? u[2] : x[0]; a0.u[3] = hi ? u[3] : x[1];
    a1.u[0] = hi ? x[6] : u[4]; a1.u[1] = hi ? x[7] : u[5];
    a1.u[2] = hi ? u[6] : x[4]; a1.u[3] = hi ? u[7] : x[5];
    // PV: O += P @ V  (B-frags from transposed Vt, ds_read_b128)
#pragma unroll
    for (int ks = 0; ks < 2; ++ks) {
      f16x8 pa = ks ? a1.h : a0.h;
      f16x8 v0 = *(const f16x8*)(Vt + (size_t)(l31) * VTS + kb + ks * 16 + hi * 8);
      f16x8 v1 = *(const f16x8*)(Vt + (size_t)(32 + l31) * VTS + kb + ks * 16 + hi * 8);
      accA = __builtin_amdgcn_mfma_f32_32x32x16_f16(pa, v0, accA, 0, 0, 0);
      accB = __builtin_amdgcn_mfma_f32_32x32x16_f16(pa, v1, accB, 0, 0, 0);
    }
  }

  // ---- epilogue
  l = l + __shfl_xor(l, 32);                    // total in-span prob mass per q
  const int dA = l31, dB = 32 + l31;
  float vsA = 0.f, vsB = 0.f;
  for (int c = c0; c < c1; ++c) { vsA += VsC[c][dA]; vsB += VsC[c][dB]; }
  const float vtA = VSg[b * 512 + h * 64 + dA];
  const float vtB = VSg[b * 512 + h * 64 + dB];
  const float zcount = (float)(S_LEN - nproc);
#pragma unroll
  for (int r = 0; r < 16; ++r) {
    int q = (r & 3) + 8 * (r >> 2) + 4 * hi;
    float mq = __shfl(m, q);
    float lq = __shfl(l, q);
    float em = __expf(-mq);
    float denom = lq + zcount * em;
    float inv = 1.0f / denom;
    size_t rowbase = ((size_t)(b * S_LEN + qw + q)) * DMODEL + h * 64;
    O[rowbase + dA] = (accA[r] + em * (vtA - vsA)) * inv;
    O[rowbase + dB] = (accB[r] + em * (vtB - vsB)) * inv;
  }
}

// ---------------- layernorm over D=512; writes f32 + f16 ----------------
__global__ void ln_kernel(const float* __restrict__ X, const float* __restrict__ g,
                          const float* __restrict__ be, float* __restrict__ Y,
                          _Float16* __restrict__ Yh) {
  int row = blockIdx.x;
  int t = threadIdx.x;
  const float* x = X + (size_t)row * DMODEL;
  float2 v = *(const float2*)(x + 2 * t);
  float s = v.x + v.y;
  float sq = v.x * v.x + v.y * v.y;
#pragma unroll
  for (int off = 32; off; off >>= 1) {
    s += __shfl_xor(s, off);
    sq += __shfl_xor(sq, off);
  }
  __shared__ float ss[4], sqq[4];
  int w = t >> 6, lane = t & 63;
  if (lane == 0) { ss[w] = s; sqq[w] = sq; }
  __syncthreads();
  s = ss[0] + ss[1] + ss[2] + ss[3];
  sq = sqq[0] + sqq[1] + sqq[2] + sqq[3];
  float mu = s * (1.0f / DMODEL);
  float var = sq * (1.0f / DMODEL) - mu * mu;
  float rstd = rsqrtf(var + 1e-5f);
  float g0 = g[2 * t], g1 = g[2 * t + 1];
  float b0 = be[2 * t], b1 = be[2 * t + 1];
  float2 o;
  o.x = (v.x - mu) * rstd * g0 + b0;
  o.y = (v.y - mu) * rstd * g1 + b1;
  *(float2*)(Y + (size_t)row * DMODEL + 2 * t) = o;
  f16x2 hh; hh[0] = (_Float16)o.x; hh[1] = (_Float16)o.y;
  *(f16x2*)(Yh + (size_t)row * DMODEL + 2 * t) = hh;
}

// ---------------- final projection ----------------
__global__ void outproj_partial_kernel(const float* __restrict__ X, const float* __restrict__ Wo,
                                       float* __restrict__ part) {
  const int KTOT = S_LEN * DMODEL;   // 524288
  const int CH = KTOT / 16;          // 32768
  int chunk = blockIdx.x, c = blockIdx.y, b = blockIdx.z;
  const float* x = X + (size_t)b * KTOT + (size_t)chunk * CH;
  const float* wv = Wo + (size_t)c * KTOT + (size_t)chunk * CH;
  float acc = 0.f;
  for (int i = threadIdx.x * 4; i < CH; i += 256 * 4) {
    float4 a = *(const float4*)(x + i);
    float4 w4 = *(const float4*)(wv + i);
    acc += a.x * w4.x + a.y * w4.y + a.z * w4.z + a.w * w4.w;
  }
#pragma unroll
  for (int off = 32; off; off >>= 1) acc += __shfl_xor(acc, off);
  __shared__ float red[4];
  int w = threadIdx.x >> 6, lane = threadIdx.x & 63;
  if (lane == 0) red[w] = acc;
  __syncthreads();
  if (threadIdx.x == 0)
    part[(b * 6 + c) * 16 + chunk] = red[0] + red[1] + red[2] + red[3];
}

__global__ void outproj_final_kernel(const float* __restrict__ part, const float* __restrict__ ob,
                                     float* __restrict__ out) {
  int idx = threadIdx.x;
  if (idx < 48) {
    float s = 0.f;
#pragma unroll
    for (int k = 0; k < 16; ++k) s += part[idx * 16 + k];
    out[idx] = s + ob[idx % 6];
  }
}

extern "C" void kernel_launch(void* const* d_in, const int* in_sizes, int n_in,
                              void* d_out, int out_size, void* d_ws, size_t ws_size,
                              hipStream_t stream) {
  (void)in_sizes; (void)n_in; (void)out_size; (void)ws_size;
  const int*   inputs = (const int*)  d_in[0];
  const float* emb    = (const float*)d_in[1];
  const float* wq     = (const float*)d_in[2];
  const float* bq     = (const float*)d_in[3];
  const float* wk     = (const float*)d_in[4];
  const float* bk     = (const float*)d_in[5];
  const float* wv     = (const float*)d_in[6];
  const float* bv     = (const float*)d_in[7];
  const float* ln_g   = (const float*)d_in[8];
  const float* ln_b   = (const float*)d_in[9];
  const float* fc1_w  = (const float*)d_in[10];
  const float* fc1_b  = (const float*)d_in[11];
  const float* fc2_w  = (const float*)d_in[12];
  const float* fc2_b  = (const float*)d_in[13];
  const float* out_w  = (const float*)d_in[14];
  const float* out_b  = (const float*)d_in[15];
  float* out = (float*)d_out;

  const int M = 8192;
  char* p = (char*)d_ws;
  float*    X    = (float*)p;      p += (size_t)M * 512 * 4;      // 16 MB
  _Float16* Xb   = (_Float16*)p;   p += (size_t)M * 512 * 2;      //  8 MB
  _Float16* QKVh = (_Float16*)p;   p += (size_t)M * 1536 * 2;     // 24 MB
  float*    XB   = (float*)p;      p += (size_t)M * 512 * 4;      // 16 MB
  _Float16* XBb  = (_Float16*)p;   p += (size_t)M * 512 * 2;      //  8 MB
  _Float16* H    = (_Float16*)p;   p += (size_t)M * 2048 * 2;     // 32 MB
  float*    Ab   = (float*)H;                                     // aliases H (dead by FC1)
  _Float16* Wqkv = (_Float16*)p;   p += (size_t)1536 * 512 * 2;
  _Float16* W1h  = (_Float16*)p;   p += (size_t)2048 * 512 * 2;
  _Float16* W2h  = (_Float16*)p;   p += (size_t)512 * 2048 * 2;
  float*    bqkv = (float*)p;      p += 1536 * 4;
  float*    VS   = (float*)p;      p += 4096 * 4;
  float*    part = (float*)p;      p += 768 * 4;

  wprep_kernel<<<4096, 256, 0, stream>>>(wq, wk, wv, bq, bk, bv, fc1_w, fc2_w,
                                         Wqkv, bqkv, W1h, W2h);
  embed_pe_kernel<<<8192, 256, 0, stream>>>(inputs, emb, X, Xb);
  for (int it = 0; it < 6; ++it) {
    mfma_gemm<EPI_F16><<<dim3(64, 12), 256, 0, stream>>>(Xb, Wqkv, bqkv, nullptr,
                                                         nullptr, QKVh, M, 1536, 512);
    vs_zero_kernel<<<16, 256, 0, stream>>>(VS);
    vsum_kernel<<<dim3(8, 8), 512, 0, stream>>>(QKVh, VS);
    attn_kernel<<<dim3(8, 8, 8), 256, 0, stream>>>(QKVh, VS, Ab);
    ln_kernel<<<8192, 256, 0, stream>>>(Ab, ln_g, ln_b, XB, XBb);
    mfma_gemm<EPI_RELU16><<<dim3(64, 16), 256, 0, stream>>>(XBb, W1h, fc1_b, nullptr,
                                                            nullptr, H, M, 2048, 512);
    mfma_gemm<EPI_RES><<<dim3(64, 4), 256, 0, stream>>>(H, W2h, fc2_b, XB,
                                                        X, nullptr, M, 512, 2048);
    ln_kernel<<<8192, 256, 0, stream>>>(X, ln_g, ln_b, X, Xb);
  }
  outproj_partial_kernel<<<dim3(16, 6, 8), 256, 0, stream>>>(X, out_w, part);
  outproj_final_kernel<<<1, 64, 0, stream>>>(part, out_b, out);
}

// Round 4
// 789.679 us; speedup vs baseline: 8.0533x; 1.1288x over previous
//
#include <hip/hip_runtime.h>

#define S_LEN 1024
#define DMODEL 512
#define NHEADS 8
#define DHEAD 64
#define HDIM 2048
#define WIN 64

typedef _Float16 f16x8 __attribute__((ext_vector_type(8)));
typedef _Float16 f16x2 __attribute__((ext_vector_type(2)));
typedef float f32x4 __attribute__((ext_vector_type(4)));
typedef float f32x16 __attribute__((ext_vector_type(16)));

__device__ __forceinline__ void stage16(const _Float16* g, _Float16* l) {
  __builtin_amdgcn_global_load_lds((const __attribute__((address_space(1))) unsigned int*)g,
                                   (__attribute__((address_space(3))) unsigned int*)l, 16, 0, 0);
}

// ---------------- weight prep: f32 -> f16, QKV concat ----------------
__global__ void wprep_kernel(const float* __restrict__ wq, const float* __restrict__ wk,
                             const float* __restrict__ wv, const float* __restrict__ bq,
                             const float* __restrict__ bk, const float* __restrict__ bv,
                             const float* __restrict__ w1, const float* __restrict__ w2,
                             _Float16* __restrict__ Wqkv, float* __restrict__ bqkv,
                             _Float16* __restrict__ W1h, _Float16* __restrict__ W2h) {
  int i = blockIdx.x * 256 + threadIdx.x;
  if (i < 262144) {
    Wqkv[i]          = (_Float16)wq[i];
    Wqkv[262144 + i] = (_Float16)wk[i];
    Wqkv[524288 + i] = (_Float16)wv[i];
  }
  if (i < 1048576) {
    W1h[i] = (_Float16)w1[i];
    W2h[i] = (_Float16)w2[i];
  }
  if (i < 512) { bqkv[i] = bq[i]; bqkv[512 + i] = bk[i]; bqkv[1024 + i] = bv[i]; }
}

// ---------------- embed + positional encoding (f32 + f16 copies) ----------------
__global__ void embed_pe_kernel(const int* __restrict__ inputs, const float* __restrict__ emb,
                                float* __restrict__ X, _Float16* __restrict__ Xb) {
  int row = blockIdx.x;          // b*S + s
  int s = row & (S_LEN - 1);
  int t = threadIdx.x;           // pair index 0..255
  int tok = inputs[row];
  float dv = __expf(-logf(10000.0f) * (2.0f * (float)t) / (float)DMODEL);
  float ang = (float)s * dv;
  float sv = sinf(ang);
  float cv = cosf(ang);
  size_t base = (size_t)row * DMODEL + 2 * t;
  float x0 = emb[(size_t)tok * DMODEL + 2 * t] + sv;
  float x1 = emb[(size_t)tok * DMODEL + 2 * t + 1] + cv;
  X[base] = x0; X[base + 1] = x1;
  f16x2 h; h[0] = (_Float16)x0; h[1] = (_Float16)x1;
  *(f16x2*)(Xb + base) = h;
}

// ---------------- MFMA f16 GEMM, 512 threads / 8 waves, 128x128 tile ----------
// A[M,Kstride] f16, W[N,Kstride] f16. Each block computes K-slice
// [z*Kslice, (z+1)*Kslice). Wave = 32x64 output (2x4 frags of 16x16x32).
// EPI: 1 relu->f16, 3 plain->f16, 4 raw f32 partial (split-K, no bias)
#define EPI_RELU16 1
#define EPI_F16 3
#define EPI_PART 4

template <int EPI>
__launch_bounds__(512)
__global__ void mfma_gemm8(const _Float16* __restrict__ A, const _Float16* __restrict__ W,
                           const float* __restrict__ bias,
                           float* __restrict__ Cf0, float* __restrict__ Cf1,
                           _Float16* __restrict__ Ch,
                           int M, int N, int Kstride, int Kslice) {
  __shared__ _Float16 As[128 * 32];
  __shared__ _Float16 Bs[128 * 32];
  const int bm = blockIdx.x * 128;
  const int bn = blockIdx.y * 128;
  const int z = blockIdx.z;
  const int t = threadIdx.x;
  const int lane = t & 63;
  const int w = t >> 6;                 // 0..7
  const int wr = w >> 1, wc = w & 1;    // wave tile: rows wr*32, cols wc*64
  const int l15 = lane & 15, l4 = lane >> 4;

  // staging: t in [0,512), row = t>>2, kgroup = (t&3)*8; LDS f16 off = t*8
  const int srow = t >> 2, skg = (t & 3) << 3;
  const _Float16* Ag = A + (size_t)(bm + srow) * Kstride + skg;
  const _Float16* Wg = W + (size_t)(bn + srow) * Kstride + skg;
  _Float16* Al = As + t * 8;
  _Float16* Bl = Bs + t * 8;

  const int kbeg = z * Kslice, kend = kbeg + Kslice;
  f32x4 acc[2][4] = {};
  for (int k0 = kbeg; k0 < kend; k0 += 32) {
    stage16(Ag + k0, Al);
    stage16(Wg + k0, Bl);
    __syncthreads();
    f16x8 af[2], bf[4];
#pragma unroll
    for (int m = 0; m < 2; ++m)
      af[m] = *(const f16x8*)&As[(wr * 32 + m * 16 + l15) * 32 + l4 * 8];
#pragma unroll
    for (int n = 0; n < 4; ++n)
      bf[n] = *(const f16x8*)&Bs[(wc * 64 + n * 16 + l15) * 32 + l4 * 8];
#pragma unroll
    for (int m = 0; m < 2; ++m)
#pragma unroll
      for (int n = 0; n < 4; ++n)
        acc[m][n] = __builtin_amdgcn_mfma_f32_16x16x32_f16(af[m], bf[n], acc[m][n], 0, 0, 0);
    __syncthreads();
  }
  float* dst = (EPI == EPI_PART) ? (z ? Cf1 : Cf0) : Cf0;
#pragma unroll
  for (int m = 0; m < 2; ++m) {
    int row = bm + wr * 32 + m * 16 + l4 * 4;
#pragma unroll
    for (int n = 0; n < 4; ++n) {
      int col = bn + wc * 64 + n * 16 + l15;
      float bb = (EPI == EPI_PART) ? 0.f : bias[col];
#pragma unroll
      for (int j = 0; j < 4; ++j) {
        float v = acc[m][n][j] + bb;
        if (EPI == EPI_RELU16) {
          v = fmaxf(v, 0.0f);
          Ch[(size_t)(row + j) * N + col] = (_Float16)v;
        } else if (EPI == EPI_F16) {
          Ch[(size_t)(row + j) * N + col] = (_Float16)v;
        } else {  // EPI_PART
          dst[(size_t)(row + j) * N + col] = v;
        }
      }
    }
  }
}

// ---------------- V column sums (full-softmax zero-correction) ----------------
__global__ void vs_zero_kernel(float* __restrict__ VS) {
  VS[blockIdx.x * 256 + threadIdx.x] = 0.0f;
}
__global__ void vsum_kernel(const _Float16* __restrict__ QKVh, float* __restrict__ VS) {
  int c = threadIdx.x;                 // 0..511 = h*64+d
  int chunk = blockIdx.x, b = blockIdx.y;
  const _Float16* base = QKVh + ((size_t)(b * S_LEN + chunk * 128)) * 1536 + 1024 + c;
  float acc = 0.f;
  for (int i = 0; i < 128; ++i) acc += (float)base[(size_t)i * 1536];
  atomicAdd(&VS[b * 512 + c], acc);
}

// ---------------- MFMA windowed attention, full-softmax zero correction --------
// grid (S/128, H, B) = (8,8,8); 256 threads = 4 waves, 32 queries per wave.
#define KTMAX 256
#define VTS 264   // Vt row stride (f16), 16B-aligned

__launch_bounds__(256)
__global__ void attn_kernel(const _Float16* __restrict__ QKVh, const float* __restrict__ VSg,
                            float* __restrict__ O) {
  __shared__ _Float16 Ks[KTMAX * 64];      // row-major, XOR-swizzled cols, 32KB
  __shared__ _Float16 Vt[64 * VTS];        // transposed V, 33KB
  __shared__ float VsC[8][64];             // per-32-key-chunk V column sums

  const int qb0 = blockIdx.x * 128, h = blockIdx.y, b = blockIdx.z;
  const int jlo = max(0, qb0 - WIN);
  const int jhi = min(S_LEN, qb0 + 128 + WIN);
  const int KT = jhi - jlo;                 // 192 or 256, multiple of 32
  const int t = threadIdx.x;
  const int lane = t & 63, w = t >> 6;
  const int hi = lane >> 5, l31 = lane & 31;

  const _Float16* Kg = QKVh + ((size_t)(b * S_LEN + jlo)) * 1536 + 512 + h * 64;
#pragma unroll
  for (int p = 0; p < 8; ++p) {
    int u = t + p * 256;                    // 0..2047
    int row = u >> 3;
    int cb = (u & 7) * 16;                  // byte col within 128B row
    int rowc = min(row, KT - 1);
    int scb = cb ^ ((row & 7) << 4);
    stage16(Kg + (size_t)rowc * 1536 + (scb >> 1), Ks + u * 8);
  }
  const _Float16* Vg = QKVh + ((size_t)(b * S_LEN + jlo)) * 1536 + 1024 + h * 64;
#pragma unroll
  for (int p = 0; p < 8; ++p) {
    int u = t + p * 256;
    int row = u >> 3;                       // key 0..255
    int d0 = (u & 7) * 8;
    f16x8 v = {0, 0, 0, 0, 0, 0, 0, 0};
    if (row < KT) v = *(const f16x8*)(Vg + (size_t)row * 1536 + d0);
#pragma unroll
    for (int e = 0; e < 8; ++e) Vt[(d0 + e) * VTS + row] = v[e];
  }
  __syncthreads();
  for (int slot = t; slot < 512; slot += 256) {
    int c = slot >> 6, d = slot & 63;
    const f16x8* col = (const f16x8*)(Vt + d * VTS + c * 32);
    float s = 0.f;
#pragma unroll
    for (int g = 0; g < 4; ++g) {
      f16x8 v = col[g];
#pragma unroll
      for (int e = 0; e < 8; ++e) s += (float)v[e];
    }
    VsC[c][d] = s;
  }
  const int qw = qb0 + w * 32;
  const _Float16* Qg = QKVh + ((size_t)(b * S_LEN + qw + l31)) * 1536 + h * 64;
  f16x8 qf[4];
#pragma unroll
  for (int ds = 0; ds < 4; ++ds) qf[ds] = *(const f16x8*)(Qg + ds * 16 + hi * 8);
  __syncthreads();

  const int c0 = max(0, qw - WIN - jlo) >> 5;
  const int c1 = min(KT, qw + 96 - jlo) >> 5;   // exclusive
  const int nproc = (c1 - c0) * 32;
  const int i = qw + l31;
  const int wlo = i - WIN, whi = i + WIN;

  float m = 0.f, l = 0.f;
  f32x16 accA = {}, accB = {};

  union PK { f16x2 h; unsigned u; };
  union A8 { unsigned u[4]; f16x8 h; };

  for (int c = c0; c < c1; ++c) {
    const int kb = c * 32;
    f32x16 sf = {};
#pragma unroll
    for (int ds = 0; ds < 4; ++ds) {
      int row = kb + l31;
      int cbyte = ((ds * 16 + hi * 8) * 2) ^ ((row & 7) << 4);
      f16x8 kf = *(const f16x8*)((const char*)Ks + row * 128 + cbyte);
      sf = __builtin_amdgcn_mfma_f32_32x32x16_f16(kf, qf[ds], sf, 0, 0, 0);
    }
    float s[16]; float pm = -1e30f;
#pragma unroll
    for (int r = 0; r < 16; ++r) {
      int gk = jlo + kb + (r & 3) + 8 * (r >> 2) + 4 * hi;
      float v = (gk >= wlo && gk < whi) ? sf[r] * 0.125f : 0.f;
      s[r] = v;
      pm = fmaxf(pm, v);
    }
    pm = fmaxf(pm, __shfl_xor(pm, 32));
    if (!__all(pm <= m + 8.f)) {
      float mn = fmaxf(m, pm);
      float f = __expf(m - mn);
      l *= f;
#pragma unroll
      for (int r = 0; r < 16; ++r) {
        int q = (r & 3) + 8 * (r >> 2) + 4 * hi;
        float fr = __shfl(f, q);
        accA[r] *= fr; accB[r] *= fr;
      }
      m = mn;
    }
    float p[16]; float ls = 0.f;
#pragma unroll
    for (int r = 0; r < 16; ++r) { p[r] = __expf(s[r] - m); ls += p[r]; }
    l += ls;
    unsigned u[8], x[8];
#pragma unroll
    for (int kk = 0; kk < 8; ++kk) {
      PK cv; cv.h[0] = (_Float16)p[2 * kk]; cv.h[1] = (_Float16)p[2 * kk + 1];
      u[kk] = cv.u;
    }
#pragma unroll
    for (int kk = 0; kk < 8; ++kk) x[kk] = (unsigned)__shfl_xor((int)u[kk], 32);
    A8 a0, a1;
    a0.u[0] = hi ? x[2] : u[0]; a0.u[1] = hi ? x[3] : u[1];
    a0.u[2] = hi ? u[2] : x[0]; a0.u[3] = hi ? u[3] : x[1];
    a1.u[0] = hi ? x[6] : u[4]; a1.u[1] = hi ? x[7] : u[5];
    a1.u[2] = hi ? u[6] : x[4]; a1.u[3] = hi ? u[7] : x[5];
#pragma unroll
    for (int ks = 0; ks < 2; ++ks) {
      f16x8 pa = ks ? a1.h : a0.h;
      f16x8 v0 = *(const f16x8*)(Vt + (size_t)(l31) * VTS + kb + ks * 16 + hi * 8);
      f16x8 v1 = *(const f16x8*)(Vt + (size_t)(32 + l31) * VTS + kb + ks * 16 + hi * 8);
      accA = __builtin_amdgcn_mfma_f32_32x32x16_f16(pa, v0, accA, 0, 0, 0);
      accB = __builtin_amdgcn_mfma_f32_32x32x16_f16(pa, v1, accB, 0, 0, 0);
    }
  }

  l = l + __shfl_xor(l, 32);
  const int dA = l31, dB = 32 + l31;
  float vsA = 0.f, vsB = 0.f;
  for (int c = c0; c < c1; ++c) { vsA += VsC[c][dA]; vsB += VsC[c][dB]; }
  const float vtA = VSg[b * 512 + h * 64 + dA];
  const float vtB = VSg[b * 512 + h * 64 + dB];
  const float zcount = (float)(S_LEN - nproc);
#pragma unroll
  for (int r = 0; r < 16; ++r) {
    int q = (r & 3) + 8 * (r >> 2) + 4 * hi;
    float mq = __shfl(m, q);
    float lq = __shfl(l, q);
    float em = __expf(-mq);
    float denom = lq + zcount * em;
    float inv = 1.0f / denom;
    size_t rowbase = ((size_t)(b * S_LEN + qw + q)) * DMODEL + h * 64;
    O[rowbase + dA] = (accA[r] + em * (vtA - vsA)) * inv;
    O[rowbase + dB] = (accB[r] + em * (vtB - vsB)) * inv;
  }
}

// ---------------- layernorm over D=512; writes f32 + f16 ----------------
__global__ void ln_kernel(const float* __restrict__ X, const float* __restrict__ g,
                          const float* __restrict__ be, float* __restrict__ Y,
                          _Float16* __restrict__ Yh) {
  int row = blockIdx.x;
  int t = threadIdx.x;
  const float* x = X + (size_t)row * DMODEL;
  float2 v = *(const float2*)(x + 2 * t);
  float s = v.x + v.y;
  float sq = v.x * v.x + v.y * v.y;
#pragma unroll
  for (int off = 32; off; off >>= 1) {
    s += __shfl_xor(s, off);
    sq += __shfl_xor(sq, off);
  }
  __shared__ float ss[4], sqq[4];
  int w = t >> 6, lane = t & 63;
  if (lane == 0) { ss[w] = s; sqq[w] = sq; }
  __syncthreads();
  s = ss[0] + ss[1] + ss[2] + ss[3];
  sq = sqq[0] + sqq[1] + sqq[2] + sqq[3];
  float mu = s * (1.0f / DMODEL);
  float var = sq * (1.0f / DMODEL) - mu * mu;
  float rstd = rsqrtf(var + 1e-5f);
  float g0 = g[2 * t], g1 = g[2 * t + 1];
  float b0 = be[2 * t], b1 = be[2 * t + 1];
  float2 o;
  o.x = (v.x - mu) * rstd * g0 + b0;
  o.y = (v.y - mu) * rstd * g1 + b1;
  *(float2*)(Y + (size_t)row * DMODEL + 2 * t) = o;
  f16x2 hh; hh[0] = (_Float16)o.x; hh[1] = (_Float16)o.y;
  *(f16x2*)(Yh + (size_t)row * DMODEL + 2 * t) = hh;
}

// ---------------- fused split-K reduce + bias + residual + layernorm ----------
__global__ void ln2_fused_kernel(const float* __restrict__ P0, const float* __restrict__ P1,
                                 const float* __restrict__ XB, const float* __restrict__ fb,
                                 const float* __restrict__ g, const float* __restrict__ be,
                                 float* __restrict__ Y, _Float16* __restrict__ Yh) {
  int row = blockIdx.x;
  int t = threadIdx.x;
  size_t off = (size_t)row * DMODEL + 2 * t;
  float2 p0 = *(const float2*)(P0 + off);
  float2 p1 = *(const float2*)(P1 + off);
  float2 xb = *(const float2*)(XB + off);
  float2 v;
  v.x = p0.x + p1.x + fb[2 * t]     + xb.x;
  v.y = p0.y + p1.y + fb[2 * t + 1] + xb.y;
  float s = v.x + v.y;
  float sq = v.x * v.x + v.y * v.y;
#pragma unroll
  for (int off2 = 32; off2; off2 >>= 1) {
    s += __shfl_xor(s, off2);
    sq += __shfl_xor(sq, off2);
  }
  __shared__ float ss[4], sqq[4];
  int w = t >> 6, lane = t & 63;
  if (lane == 0) { ss[w] = s; sqq[w] = sq; }
  __syncthreads();
  s = ss[0] + ss[1] + ss[2] + ss[3];
  sq = sqq[0] + sqq[1] + sqq[2] + sqq[3];
  float mu = s * (1.0f / DMODEL);
  float var = sq * (1.0f / DMODEL) - mu * mu;
  float rstd = rsqrtf(var + 1e-5f);
  float g0 = g[2 * t], g1 = g[2 * t + 1];
  float b0 = be[2 * t], b1 = be[2 * t + 1];
  float2 o;
  o.x = (v.x - mu) * rstd * g0 + b0;
  o.y = (v.y - mu) * rstd * g1 + b1;
  *(float2*)(Y + off) = o;
  f16x2 hh; hh[0] = (_Float16)o.x; hh[1] = (_Float16)o.y;
  *(f16x2*)(Yh + off) = hh;
}

// ---------------- final projection ----------------
__global__ void outproj_partial_kernel(const float* __restrict__ X, const float* __restrict__ Wo,
                                       float* __restrict__ part) {
  const int KTOT = S_LEN * DMODEL;   // 524288
  const int CH = KTOT / 16;          // 32768
  int chunk = blockIdx.x, c = blockIdx.y, b = blockIdx.z;
  const float* x = X + (size_t)b * KTOT + (size_t)chunk * CH;
  const float* wv = Wo + (size_t)c * KTOT + (size_t)chunk * CH;
  float acc = 0.f;
  for (int i = threadIdx.x * 4; i < CH; i += 256 * 4) {
    float4 a = *(const float4*)(x + i);
    float4 w4 = *(const float4*)(wv + i);
    acc += a.x * w4.x + a.y * w4.y + a.z * w4.z + a.w * w4.w;
  }
#pragma unroll
  for (int off = 32; off; off >>= 1) acc += __shfl_xor(acc, off);
  __shared__ float red[4];
  int w = threadIdx.x >> 6, lane = threadIdx.x & 63;
  if (lane == 0) red[w] = acc;
  __syncthreads();
  if (threadIdx.x == 0)
    part[(b * 6 + c) * 16 + chunk] = red[0] + red[1] + red[2] + red[3];
}

__global__ void outproj_final_kernel(const float* __restrict__ part, const float* __restrict__ ob,
                                     float* __restrict__ out) {
  int idx = threadIdx.x;
  if (idx < 48) {
    float s = 0.f;
#pragma unroll
    for (int k = 0; k < 16; ++k) s += part[idx * 16 + k];
    out[idx] = s + ob[idx % 6];
  }
}

extern "C" void kernel_launch(void* const* d_in, const int* in_sizes, int n_in,
                              void* d_out, int out_size, void* d_ws, size_t ws_size,
                              hipStream_t stream) {
  (void)in_sizes; (void)n_in; (void)out_size; (void)ws_size;
  const int*   inputs = (const int*)  d_in[0];
  const float* emb    = (const float*)d_in[1];
  const float* wq     = (const float*)d_in[2];
  const float* bq     = (const float*)d_in[3];
  const float* wk     = (const float*)d_in[4];
  const float* bk     = (const float*)d_in[5];
  const float* wv     = (const float*)d_in[6];
  const float* bv     = (const float*)d_in[7];
  const float* ln_g   = (const float*)d_in[8];
  const float* ln_b   = (const float*)d_in[9];
  const float* fc1_w  = (const float*)d_in[10];
  const float* fc1_b  = (const float*)d_in[11];
  const float* fc2_w  = (const float*)d_in[12];
  const float* fc2_b  = (const float*)d_in[13];
  const float* out_w  = (const float*)d_in[14];
  const float* out_b  = (const float*)d_in[15];
  float* out = (float*)d_out;

  const int M = 8192;
  char* p = (char*)d_ws;
  float*    X    = (float*)p;      p += (size_t)M * 512 * 4;      // 16 MB (doubles as P0)
  _Float16* Xb   = (_Float16*)p;   p += (size_t)M * 512 * 2;      //  8 MB
  _Float16* QKVh = (_Float16*)p;   p += (size_t)M * 1536 * 2;     // 24 MB (doubles as P1)
  float*    XB   = (float*)p;      p += (size_t)M * 512 * 4;      // 16 MB
  _Float16* XBb  = (_Float16*)p;   p += (size_t)M * 512 * 2;      //  8 MB
  _Float16* H    = (_Float16*)p;   p += (size_t)M * 2048 * 2;     // 32 MB
  float*    Ab   = (float*)H;                                     // aliases H (dead by FC1)
  _Float16* Wqkv = (_Float16*)p;   p += (size_t)1536 * 512 * 2;
  _Float16* W1h  = (_Float16*)p;   p += (size_t)2048 * 512 * 2;
  _Float16* W2h  = (_Float16*)p;   p += (size_t)512 * 2048 * 2;
  float*    bqkv = (float*)p;      p += 1536 * 4;
  float*    VS   = (float*)p;      p += 4096 * 4;
  float*    part = (float*)p;      p += 768 * 4;
  float*    P0   = X;                 // X f32 dead during loop (only outproj reads it)
  float*    P1   = (float*)QKVh;      // QKV dead after attn; FC2 runs later

  wprep_kernel<<<4096, 256, 0, stream>>>(wq, wk, wv, bq, bk, bv, fc1_w, fc2_w,
                                         Wqkv, bqkv, W1h, W2h);
  embed_pe_kernel<<<8192, 256, 0, stream>>>(inputs, emb, X, Xb);
  for (int it = 0; it < 6; ++it) {
    mfma_gemm8<EPI_F16><<<dim3(64, 12), 512, 0, stream>>>(Xb, Wqkv, bqkv, nullptr, nullptr,
                                                          QKVh, M, 1536, 512, 512);
    vs_zero_kernel<<<16, 256, 0, stream>>>(VS);
    vsum_kernel<<<dim3(8, 8), 512, 0, stream>>>(QKVh, VS);
    attn_kernel<<<dim3(8, 8, 8), 256, 0, stream>>>(QKVh, VS, Ab);
    ln_kernel<<<8192, 256, 0, stream>>>(Ab, ln_g, ln_b, XB, XBb);
    mfma_gemm8<EPI_RELU16><<<dim3(64, 16), 512, 0, stream>>>(XBb, W1h, fc1_b, nullptr, nullptr,
                                                             H, M, 2048, 512, 512);
    mfma_gemm8<EPI_PART><<<dim3(64, 4, 2), 512, 0, stream>>>(H, W2h, nullptr, P0, P1,
                                                             nullptr, M, 512, 2048, 1024);
    ln2_fused_kernel<<<8192, 256, 0, stream>>>(P0, P1, XB, fc2_b, ln_g, ln_b, X, Xb);
  }
  outproj_partial_kernel<<<dim3(16, 6, 8), 256, 0, stream>>>(X, out_w, part);
  outproj_final_kernel<<<1, 64, 0, stream>>>(part, out_b, out);
}